// Round 1
// baseline (136.647 us; speedup 1.0000x reference)
//
#include <hip/hip_runtime.h>
#include <hip/hip_bf16.h>

// Problem constants
#define BB 8
#define TT_ 4
#define TSEQ 1024
#define CEMB 512
#define NH 8
#define HD 64

typedef __attribute__((ext_vector_type(8))) short bf16x8;
typedef __attribute__((ext_vector_type(4))) float f32x4;

#define AS1 __attribute__((address_space(1)))
#define AS3 __attribute__((address_space(3)))

__device__ __forceinline__ void gload_lds16(const void* g, void* l) {
  __builtin_amdgcn_global_load_lds((const AS1 unsigned int*)g, (AS3 unsigned int*)l, 16, 0, 0);
}

__device__ __forceinline__ short f2b(float f) {
  union { float f; unsigned u; } v; v.f = f;
  unsigned r = v.u + 0x7FFFu + ((v.u >> 16) & 1u);
  return (short)(r >> 16);
}

// ---------------------------------------------------------------------------
// Mask dtype detection + expansion. padding_mask is [TT,T] bool in numpy; the
// device buffer may be u8 / i32 / f32 / u16(bf16|f16). Detect by value
// pattern over the first 4096 bytes (safe for all layouts), then expand to
// int32 pm[tt*T + q].
// ---------------------------------------------------------------------------
__global__ __launch_bounds__(256) void k_mask(const void* __restrict__ pin, int* __restrict__ pme) {
  __shared__ int bad_f32, any_f32, bad_i32, any_i32, bad_u16, any_u16;
  if (threadIdx.x == 0) { bad_f32 = any_f32 = bad_i32 = any_i32 = bad_u16 = any_u16 = 0; }
  __syncthreads();
  const unsigned char* pb = (const unsigned char*)pin;
  const float* pf = (const float*)pin;
  const int* pi = (const int*)pin;
  const unsigned short* ph = (const unsigned short*)pin;
  for (int i = threadIdx.x; i < 1024; i += 256) {      // first 4096 bytes
    float fv = pf[i];
    if (fv != 0.0f && fv != 1.0f) bad_f32 = 1;
    if (fv == 1.0f) any_f32 = 1;
    int iv = pi[i];
    if (iv != 0 && iv != 1) bad_i32 = 1;
    if (iv == 1) any_i32 = 1;
  }
  for (int i = threadIdx.x; i < 2048; i += 256) {
    unsigned short hv = ph[i];
    if (hv != 0 && hv != 0x3F80u && hv != 0x3C00u) bad_u16 = 1;
    if (hv == 0x3F80u || hv == 0x3C00u) any_u16 = 1;
  }
  __syncthreads();
  int mode = 3;                                        // default: u8
  if (!bad_f32 && any_f32) mode = 0;
  else if (!bad_i32 && any_i32) mode = 1;
  else if (!bad_u16 && any_u16) mode = 2;
  for (int i = threadIdx.x; i < TT_ * TSEQ; i += 256) {
    int v;
    if (mode == 0)      v = (pf[i] != 0.0f);
    else if (mode == 1) v = (pi[i] != 0);
    else if (mode == 2) v = (ph[i] != 0);
    else                v = (pb[i] != 0);
    pme[i] = v;
  }
}

// x f32 -> bf16 (vectorized)
__global__ __launch_bounds__(256) void k_cvt_x(const float* __restrict__ x, short* __restrict__ xb, int n4) {
  int i = blockIdx.x * 256 + threadIdx.x;
  if (i < n4) {
    float4 v = ((const float4*)x)[i];
    short4 o;
    o.x = f2b(v.x); o.y = f2b(v.y); o.z = f2b(v.z); o.w = f2b(v.w);
    ((short4*)xb)[i] = o;
  }
}

// W [K][N] f32 -> Wt [N][K] bf16
__global__ __launch_bounds__(256) void k_transpose_w(const float* __restrict__ w, short* __restrict__ wt,
                                                     int K, int N) {
  int id = blockIdx.x * 256 + threadIdx.x;
  if (id < K * N) {
    int n = id / K, k = id % K;
    wt[id] = f2b(w[(size_t)k * N + n]);
  }
}

// ---------------------------------------------------------------------------
// GEMM: C[M,N] = A[M,512] * Bt[N,512]^T + bias. 128x128 tile, 4 waves (2x2),
// BK=32, global_load_lds(16B) staging, mfma 16x16x32 bf16.
// MODE 0: QKV epilogue -> q[B,H,T,D], k[B,H,T,D], vT[B,H,D,T] (bf16)
// MODE 1: f32 output [M,512]
// ---------------------------------------------------------------------------
template<int MODE>
__global__ __launch_bounds__(256) void k_gemm(
    const short* __restrict__ A, const short* __restrict__ Bt,
    const float* __restrict__ bias,
    short* __restrict__ qb, short* __restrict__ kb, short* __restrict__ vtb,
    float* __restrict__ fout)
{
  __shared__ short As[128 * 32];
  __shared__ short Bs[128 * 32];
  const int tid = threadIdx.x, lane = tid & 63, w = tid >> 6;
  const int wm = w >> 1, wn = w & 1;
  const int n0 = blockIdx.x * 128, m0 = blockIdx.y * 128;
  f32x4 acc[4][4] = {};
  const char* Abase = (const char*)A + (size_t)m0 * 1024;   // row stride 512*2=1024B
  const char* Bbase = (const char*)Bt + (size_t)n0 * 1024;
  const int rowL = w * 16 + (lane >> 2);
  const int colB = (lane & 3) * 16;

  for (int k0 = 0; k0 < 512; k0 += 32) {
    __syncthreads();
#pragma unroll
    for (int is = 0; is < 2; ++is) {
      int row = is * 64 + rowL;
      gload_lds16(Abase + (size_t)row * 1024 + (size_t)(k0 * 2 + colB),
                  (char*)As + is * 4096 + w * 1024);
      gload_lds16(Bbase + (size_t)row * 1024 + (size_t)(k0 * 2 + colB),
                  (char*)Bs + is * 4096 + w * 1024);
    }
    __syncthreads();
    bf16x8 a[4], bfr[4];
#pragma unroll
    for (int mf = 0; mf < 4; ++mf)
      a[mf] = *(const bf16x8*)&As[(wm * 64 + mf * 16 + (lane & 15)) * 32 + (lane >> 4) * 8];
#pragma unroll
    for (int nf = 0; nf < 4; ++nf)
      bfr[nf] = *(const bf16x8*)&Bs[(wn * 64 + nf * 16 + (lane & 15)) * 32 + (lane >> 4) * 8];
#pragma unroll
    for (int mf = 0; mf < 4; ++mf)
#pragma unroll
      for (int nf = 0; nf < 4; ++nf)
        acc[mf][nf] = __builtin_amdgcn_mfma_f32_16x16x32_bf16(a[mf], bfr[nf], acc[mf][nf], 0, 0, 0);
  }

#pragma unroll
  for (int nf = 0; nf < 4; ++nf) {
    const int n_g = n0 + wn * 64 + nf * 16 + (lane & 15);
    const float bv = bias[n_g];
    if (MODE == 0) {
      const int which = n_g >> 9;       // 0=q 1=k 2=v
      const int c = n_g & 511;
      const int h = c >> 6, d = c & 63;
#pragma unroll
      for (int mf = 0; mf < 4; ++mf) {
        const int mb = m0 + wm * 64 + mf * 16 + ((lane >> 4) << 2);
        const int b = mb >> 10, t0 = mb & 1023;
        const int b8h = b * NH + h;
        if (which == 2) {
          short4 pk;
          pk.x = f2b(acc[mf][nf][0] + bv);
          pk.y = f2b(acc[mf][nf][1] + bv);
          pk.z = f2b(acc[mf][nf][2] + bv);
          pk.w = f2b(acc[mf][nf][3] + bv);
          *(short4*)&vtb[((size_t)b8h * HD + d) * TSEQ + t0] = pk;
        } else {
          short* dst = (which == 0) ? qb : kb;
          size_t base = ((size_t)b8h * TSEQ + t0) * HD + d;
#pragma unroll
          for (int r = 0; r < 4; ++r)
            dst[base + (size_t)r * HD] = f2b(acc[mf][nf][r] + bv);
        }
      }
    } else {
#pragma unroll
      for (int mf = 0; mf < 4; ++mf) {
        const int mb = m0 + wm * 64 + mf * 16 + ((lane >> 4) << 2);
#pragma unroll
        for (int r = 0; r < 4; ++r)
          fout[(size_t)(mb + r) * 512 + n_g] = acc[mf][nf][r] + bv;
      }
    }
  }
}

// ---------------------------------------------------------------------------
// Flash attention. Block = (q-tile of 128, one (b,h)). 4 waves x 32 q-rows.
// KT=64 keys/tile. K,V^T staged to LDS via global_load_lds with XOR-swizzled
// global source (linear LDS dest); P via swizzled ds_write/ds_read.
// mask: attend = (k<=q) || pm[b%4][q]
// ---------------------------------------------------------------------------
__global__ __launch_bounds__(256) void k_attn(
    const short* __restrict__ qg, const short* __restrict__ kg,
    const short* __restrict__ vtg, const int* __restrict__ pme,
    short* __restrict__ yb)
{
  __shared__ short Ks[64 * 64];      // [key][d], 128B rows, chunk c at c^(key&7)
  __shared__ short Vs[64 * 64];      // [d][key], 128B rows, chunk c at c^(d&7)
  __shared__ short Ps[128 * 64];     // [q_l][key], 128B rows, chunk c at c^(q&7)
  __shared__ int s_haspm;
  const int tid = threadIdx.x, lane = tid & 63, w = tid >> 6;
  const int bh = blockIdx.y, b = bh >> 3, h = bh & 7, tt = b & 3;
  const int q0 = blockIdx.x << 7;
  const char* Qb = (const char*)(qg + ((size_t)bh * TSEQ + q0) * HD);
  const char* Kb = (const char*)(kg + (size_t)bh * TSEQ * HD);
  const char* Vb = (const char*)(vtg + (size_t)bh * HD * TSEQ);

  if (tid == 0) s_haspm = 0;
  __syncthreads();
  if (tid < 128 && pme[tt * TSEQ + q0 + tid]) s_haspm = 1;
  __syncthreads();
  const int nkt = s_haspm ? (TSEQ / 64) : ((q0 >> 6) + 2);

  // Q fragments (held in registers for the whole block)
  bf16x8 qa[2][2];
#pragma unroll
  for (int mf = 0; mf < 2; ++mf)
#pragma unroll
    for (int kk = 0; kk < 2; ++kk)
      qa[mf][kk] = *(const bf16x8*)(Qb + (size_t)(w * 32 + mf * 16 + (lane & 15)) * 128
                                       + kk * 64 + (lane >> 4) * 16);

  float pmv[2][4], mrun[2][4], lrun[2][4];
  f32x4 acc_o[2][4] = {};
#pragma unroll
  for (int mf = 0; mf < 2; ++mf)
#pragma unroll
    for (int r = 0; r < 4; ++r) {
      int q_g = q0 + w * 32 + mf * 16 + ((lane >> 4) << 2) + r;
      pmv[mf][r] = pme[tt * TSEQ + q_g] ? 1.0f : 0.0f;
      mrun[mf][r] = -__builtin_inff();
      lrun[mf][r] = 0.0f;
    }

  for (int kt = 0; kt < nkt; ++kt) {
    __syncthreads();
#pragma unroll
    for (int is = 0; is < 2; ++is) {
      int row = is * 32 + (w << 3) + (lane >> 3);
      int cl = (lane & 7) ^ ((lane >> 3) & 7);          // pre-swizzled source chunk
      gload_lds16(Kb + (size_t)(kt * 64 + row) * 128 + cl * 16,
                  (char*)Ks + is * 4096 + w * 1024);
      gload_lds16(Vb + (size_t)row * 2048 + kt * 128 + cl * 16,
                  (char*)Vs + is * 4096 + w * 1024);
    }
    __syncthreads();

    // S = Q K^T
    f32x4 accs[2][4] = {};
#pragma unroll
    for (int kk = 0; kk < 2; ++kk) {
      bf16x8 kf[4];
#pragma unroll
      for (int nf = 0; nf < 4; ++nf) {
        int key = nf * 16 + (lane & 15);
        int phys = (kk * 4 + (lane >> 4)) ^ (key & 7);
        kf[nf] = *(const bf16x8*)((const char*)Ks + key * 128 + phys * 16);
      }
#pragma unroll
      for (int mf = 0; mf < 2; ++mf)
#pragma unroll
        for (int nf = 0; nf < 4; ++nf)
          accs[mf][nf] = __builtin_amdgcn_mfma_f32_16x16x32_bf16(qa[mf][kk], kf[nf], accs[mf][nf], 0, 0, 0);
    }

    // scale + mask
    const int kbase = kt * 64;
#pragma unroll
    for (int mf = 0; mf < 2; ++mf)
#pragma unroll
      for (int r = 0; r < 4; ++r) {
        int q_g = q0 + w * 32 + mf * 16 + ((lane >> 4) << 2) + r;
        bool pm = (pmv[mf][r] != 0.0f);
#pragma unroll
        for (int nf = 0; nf < 4; ++nf) {
          int key_g = kbase + nf * 16 + (lane & 15);
          float sv = accs[mf][nf][r] * 0.125f;
          accs[mf][nf][r] = ((key_g <= q_g) || pm) ? sv : -1e30f;
        }
      }

    // online softmax
#pragma unroll
    for (int mf = 0; mf < 2; ++mf)
#pragma unroll
      for (int r = 0; r < 4; ++r) {
        float mx = accs[mf][0][r];
#pragma unroll
        for (int nf = 1; nf < 4; ++nf) mx = fmaxf(mx, accs[mf][nf][r]);
        mx = fmaxf(mx, __shfl_xor(mx, 1, 64));
        mx = fmaxf(mx, __shfl_xor(mx, 2, 64));
        mx = fmaxf(mx, __shfl_xor(mx, 4, 64));
        mx = fmaxf(mx, __shfl_xor(mx, 8, 64));
        float mo = mrun[mf][r];
        float nm = fmaxf(mo, mx);
        float sc = __expf(mo - nm);
        mrun[mf][r] = nm;
        float rs = 0.0f;
#pragma unroll
        for (int nf = 0; nf < 4; ++nf) {
          float p = __expf(accs[mf][nf][r] - nm);
          accs[mf][nf][r] = p;
          rs += p;
        }
        rs += __shfl_xor(rs, 1, 64);
        rs += __shfl_xor(rs, 2, 64);
        rs += __shfl_xor(rs, 4, 64);
        rs += __shfl_xor(rs, 8, 64);
        lrun[mf][r] = lrun[mf][r] * sc + rs;
#pragma unroll
        for (int nf = 0; nf < 4; ++nf) acc_o[mf][nf][r] *= sc;
      }

    // P -> LDS (bf16, swizzled)
#pragma unroll
    for (int mf = 0; mf < 2; ++mf)
#pragma unroll
      for (int nf = 0; nf < 4; ++nf)
#pragma unroll
        for (int r = 0; r < 4; ++r) {
          int q_l = w * 32 + mf * 16 + ((lane >> 4) << 2) + r;
          int key = nf * 16 + (lane & 15);
          int phys = (key >> 3) ^ (q_l & 7);
          *(short*)((char*)Ps + q_l * 128 + phys * 16 + (key & 7) * 2) = f2b(accs[mf][nf][r]);
        }

    // O += P V
#pragma unroll
    for (int kk2 = 0; kk2 < 2; ++kk2) {
      bf16x8 pa[2], vf[4];
#pragma unroll
      for (int mf = 0; mf < 2; ++mf) {
        int q_l = w * 32 + mf * 16 + (lane & 15);
        int phys = (kk2 * 4 + (lane >> 4)) ^ (q_l & 7);
        pa[mf] = *(const bf16x8*)((const char*)Ps + q_l * 128 + phys * 16);
      }
#pragma unroll
      for (int nf = 0; nf < 4; ++nf) {
        int d = nf * 16 + (lane & 15);
        int phys = (kk2 * 4 + (lane >> 4)) ^ (d & 7);
        vf[nf] = *(const bf16x8*)((const char*)Vs + d * 128 + phys * 16);
      }
#pragma unroll
      for (int mf = 0; mf < 2; ++mf)
#pragma unroll
        for (int nf = 0; nf < 4; ++nf)
          acc_o[mf][nf] = __builtin_amdgcn_mfma_f32_16x16x32_bf16(pa[mf], vf[nf], acc_o[mf][nf], 0, 0, 0);
    }
  }

  // epilogue: y[b][t][h*64+d] bf16
#pragma unroll
  for (int mf = 0; mf < 2; ++mf)
#pragma unroll
    for (int nf = 0; nf < 4; ++nf)
#pragma unroll
      for (int r = 0; r < 4; ++r) {
        int q_g = q0 + w * 32 + mf * 16 + ((lane >> 4) << 2) + r;
        int d = nf * 16 + (lane & 15);
        float o = acc_o[mf][nf][r] / lrun[mf][r];
        yb[((size_t)b * TSEQ + q_g) * CEMB + h * HD + d] = f2b(o);
      }
}

// ---------------------------------------------------------------------------
extern "C" void kernel_launch(void* const* d_in, const int* in_sizes, int n_in,
                              void* d_out, int out_size, void* d_ws, size_t ws_size,
                              hipStream_t stream) {
  const float* x     = (const float*)d_in[0];
  const void*  pmask = d_in[1];
  const float* Wqkv  = (const float*)d_in[2];
  const float* bqkv  = (const float*)d_in[3];
  const float* Wproj = (const float*)d_in[4];
  const float* bproj = (const float*)d_in[5];
  float* out = (float*)d_out;
  char* ws = (char*)d_ws;

  // workspace layout (bytes)
  const size_t OFF_XB  = 0;          // 8 MiB  x bf16 [8192][512]
  const size_t OFF_WQT = 8388608;    // 1.5MiB WqkvT bf16 [1536][512]
  const size_t OFF_WPT = 9961472;    // 0.5MiB WprojT bf16 [512][512]
  const size_t OFF_Q   = 10485760;   // 8 MiB  q bf16 [B,H,T,D]
  const size_t OFF_K   = 18874368;   // 8 MiB  k bf16 [B,H,T,D]
  const size_t OFF_VT  = 27262976;   // 8 MiB  vT bf16 [B,H,D,T]
  const size_t OFF_Y   = 35651584;   // 8 MiB  y bf16 [B,T,C]
  const size_t OFF_PM  = 44040192;   // 16 KiB pm int32 [TT,T]
  const size_t NEED    = 44056576;
  if (ws_size < NEED) return;  // workspace too small; fail loudly (output stays poison)

  short* xb  = (short*)(ws + OFF_XB);
  short* wqT = (short*)(ws + OFF_WQT);
  short* wpT = (short*)(ws + OFF_WPT);
  short* qb  = (short*)(ws + OFF_Q);
  short* kb  = (short*)(ws + OFF_K);
  short* vtb = (short*)(ws + OFF_VT);
  short* yb  = (short*)(ws + OFF_Y);
  int*   pme = (int*)(ws + OFF_PM);

  k_mask<<<dim3(1), dim3(256), 0, stream>>>(pmask, pme);
  k_cvt_x<<<dim3(4096), dim3(256), 0, stream>>>(x, xb, (BB * TSEQ * CEMB) / 4);
  k_transpose_w<<<dim3((CEMB * 3 * CEMB + 255) / 256), dim3(256), 0, stream>>>(Wqkv, wqT, CEMB, 3 * CEMB);
  k_transpose_w<<<dim3((CEMB * CEMB + 255) / 256), dim3(256), 0, stream>>>(Wproj, wpT, CEMB, CEMB);
  k_gemm<0><<<dim3(12, 64), dim3(256), 0, stream>>>(xb, wqT, bqkv, qb, kb, vtb, nullptr);
  k_attn<<<dim3(8, 64), dim3(256), 0, stream>>>(qb, kb, vtb, pme, yb);
  k_gemm<1><<<dim3(4, 64), dim3(256), 0, stream>>>(yb, wpT, bproj, nullptr, nullptr, nullptr, out);
}

// Round 2
// 113.624 us; speedup vs baseline: 1.2026x; 1.2026x over previous
//
#include <hip/hip_runtime.h>
#include <hip/hip_bf16.h>

// Problem constants
#define BB 8
#define TT_ 4
#define TSEQ 1024
#define CEMB 512
#define NH 8
#define HD 64

typedef __attribute__((ext_vector_type(8))) short bf16x8;
typedef __attribute__((ext_vector_type(4))) float f32x4;
typedef __attribute__((ext_vector_type(16))) float f32x16;

#define AS1 __attribute__((address_space(1)))
#define AS3 __attribute__((address_space(3)))

__device__ __forceinline__ void gload_lds16(const void* g, void* l) {
  __builtin_amdgcn_global_load_lds((const AS1 unsigned int*)g, (AS3 unsigned int*)l, 16, 0, 0);
}

__device__ __forceinline__ short f2b(float f) {
  union { float f; unsigned u; } v; v.f = f;
  unsigned r = v.u + 0x7FFFu + ((v.u >> 16) & 1u);
  return (short)(r >> 16);
}

__device__ __forceinline__ unsigned pack2(float a, float b) {
  return (unsigned)(unsigned short)f2b(a) | ((unsigned)(unsigned short)f2b(b) << 16);
}

// ---------------------------------------------------------------------------
// Mask dtype detection + expansion (unchanged).
// ---------------------------------------------------------------------------
__global__ __launch_bounds__(256) void k_mask(const void* __restrict__ pin, int* __restrict__ pme) {
  __shared__ int bad_f32, any_f32, bad_i32, any_i32, bad_u16, any_u16;
  if (threadIdx.x == 0) { bad_f32 = any_f32 = bad_i32 = any_i32 = bad_u16 = any_u16 = 0; }
  __syncthreads();
  const unsigned char* pb = (const unsigned char*)pin;
  const float* pf = (const float*)pin;
  const int* pi = (const int*)pin;
  const unsigned short* ph = (const unsigned short*)pin;
  for (int i = threadIdx.x; i < 1024; i += 256) {
    float fv = pf[i];
    if (fv != 0.0f && fv != 1.0f) bad_f32 = 1;
    if (fv == 1.0f) any_f32 = 1;
    int iv = pi[i];
    if (iv != 0 && iv != 1) bad_i32 = 1;
    if (iv == 1) any_i32 = 1;
  }
  for (int i = threadIdx.x; i < 2048; i += 256) {
    unsigned short hv = ph[i];
    if (hv != 0 && hv != 0x3F80u && hv != 0x3C00u) bad_u16 = 1;
    if (hv == 0x3F80u || hv == 0x3C00u) any_u16 = 1;
  }
  __syncthreads();
  int mode = 3;
  if (!bad_f32 && any_f32) mode = 0;
  else if (!bad_i32 && any_i32) mode = 1;
  else if (!bad_u16 && any_u16) mode = 2;
  for (int i = threadIdx.x; i < TT_ * TSEQ; i += 256) {
    int v;
    if (mode == 0)      v = (pf[i] != 0.0f);
    else if (mode == 1) v = (pi[i] != 0);
    else if (mode == 2) v = (ph[i] != 0);
    else                v = (pb[i] != 0);
    pme[i] = v;
  }
}

__global__ __launch_bounds__(256) void k_cvt_x(const float* __restrict__ x, short* __restrict__ xb, int n4) {
  int i = blockIdx.x * 256 + threadIdx.x;
  if (i < n4) {
    float4 v = ((const float4*)x)[i];
    short4 o;
    o.x = f2b(v.x); o.y = f2b(v.y); o.z = f2b(v.z); o.w = f2b(v.w);
    ((short4*)xb)[i] = o;
  }
}

__global__ __launch_bounds__(256) void k_transpose_w(const float* __restrict__ w, short* __restrict__ wt,
                                                     int K, int N) {
  int id = blockIdx.x * 256 + threadIdx.x;
  if (id < K * N) {
    int n = id / K, k = id % K;
    wt[id] = f2b(w[(size_t)k * N + n]);
  }
}

// ---------------------------------------------------------------------------
// GEMM (unchanged from round 1): 128x128 tile, 4 waves, BK=32.
// ---------------------------------------------------------------------------
template<int MODE>
__global__ __launch_bounds__(256) void k_gemm(
    const short* __restrict__ A, const short* __restrict__ Bt,
    const float* __restrict__ bias,
    short* __restrict__ qb, short* __restrict__ kb, short* __restrict__ vtb,
    float* __restrict__ fout)
{
  __shared__ short As[128 * 32];
  __shared__ short Bs[128 * 32];
  const int tid = threadIdx.x, lane = tid & 63, w = tid >> 6;
  const int wm = w >> 1, wn = w & 1;
  const int n0 = blockIdx.x * 128, m0 = blockIdx.y * 128;
  f32x4 acc[4][4] = {};
  const char* Abase = (const char*)A + (size_t)m0 * 1024;
  const char* Bbase = (const char*)Bt + (size_t)n0 * 1024;
  const int rowL = w * 16 + (lane >> 2);
  const int colB = (lane & 3) * 16;

  for (int k0 = 0; k0 < 512; k0 += 32) {
    __syncthreads();
#pragma unroll
    for (int is = 0; is < 2; ++is) {
      int row = is * 64 + rowL;
      gload_lds16(Abase + (size_t)row * 1024 + (size_t)(k0 * 2 + colB),
                  (char*)As + is * 4096 + w * 1024);
      gload_lds16(Bbase + (size_t)row * 1024 + (size_t)(k0 * 2 + colB),
                  (char*)Bs + is * 4096 + w * 1024);
    }
    __syncthreads();
    bf16x8 a[4], bfr[4];
#pragma unroll
    for (int mf = 0; mf < 4; ++mf)
      a[mf] = *(const bf16x8*)&As[(wm * 64 + mf * 16 + (lane & 15)) * 32 + (lane >> 4) * 8];
#pragma unroll
    for (int nf = 0; nf < 4; ++nf)
      bfr[nf] = *(const bf16x8*)&Bs[(wn * 64 + nf * 16 + (lane & 15)) * 32 + (lane >> 4) * 8];
#pragma unroll
    for (int mf = 0; mf < 4; ++mf)
#pragma unroll
      for (int nf = 0; nf < 4; ++nf)
        acc[mf][nf] = __builtin_amdgcn_mfma_f32_16x16x32_bf16(a[mf], bfr[nf], acc[mf][nf], 0, 0, 0);
  }

#pragma unroll
  for (int nf = 0; nf < 4; ++nf) {
    const int n_g = n0 + wn * 64 + nf * 16 + (lane & 15);
    const float bv = bias[n_g];
    if (MODE == 0) {
      const int which = n_g >> 9;
      const int c = n_g & 511;
      const int h = c >> 6, d = c & 63;
#pragma unroll
      for (int mf = 0; mf < 4; ++mf) {
        const int mb = m0 + wm * 64 + mf * 16 + ((lane >> 4) << 2);
        const int b = mb >> 10, t0 = mb & 1023;
        const int b8h = b * NH + h;
        if (which == 2) {
          short4 pk;
          pk.x = f2b(acc[mf][nf][0] + bv);
          pk.y = f2b(acc[mf][nf][1] + bv);
          pk.z = f2b(acc[mf][nf][2] + bv);
          pk.w = f2b(acc[mf][nf][3] + bv);
          *(short4*)&vtb[((size_t)b8h * HD + d) * TSEQ + t0] = pk;
        } else {
          short* dst = (which == 0) ? qb : kb;
          size_t base = ((size_t)b8h * TSEQ + t0) * HD + d;
#pragma unroll
          for (int r = 0; r < 4; ++r)
            dst[base + (size_t)r * HD] = f2b(acc[mf][nf][r] + bv);
        }
      }
    } else {
#pragma unroll
      for (int mf = 0; mf < 4; ++mf) {
        const int mb = m0 + wm * 64 + mf * 16 + ((lane >> 4) << 2);
#pragma unroll
        for (int r = 0; r < 4; ++r)
          fout[(size_t)(mb + r) * 512 + n_g] = acc[mf][nf][r] + bv;
      }
    }
  }
}

// ---------------------------------------------------------------------------
// Flash attention v2 — swapped-operand 32x32 structure (m214 port).
// 4 waves x 32 q-rows = 128 q/block. KV-tile = 64 keys.
// S^T = K·Q^T  (mfma_32x32x16: lane owns q = lane&31, 32 of 64 keys)
// softmax: lane-local 31-fmax + ONE shfl_xor(32); P stays in registers
// O^T = V^T·P (acc cols = q = lane&31 -> lane-local rescale/normalize)
// K/V staged via global_load_lds with XOR-swizzled global source.
// XCD-aware 1D grid: bh = id&63 (id%8 = bh%8 -> all q-tiles of a bh on 1 XCD)
// ---------------------------------------------------------------------------
__device__ __forceinline__ void pv_step(
    f32x16 p, int sub, int hi, int lq, const char* Vsb, f32x16& o0, f32x16& o1)
{
  unsigned P2[8];
#pragma unroll
  for (int i = 0; i < 8; ++i) P2[i] = pack2(p[2 * i], p[2 * i + 1]);
  // exchange complementary key-halves with partner lane (same q, lane^32)
  unsigned e0 = __shfl_xor(hi ? P2[0] : P2[2], 32, 64);
  unsigned e1 = __shfl_xor(hi ? P2[1] : P2[3], 32, 64);
  unsigned e2 = __shfl_xor(hi ? P2[4] : P2[6], 32, 64);
  unsigned e3 = __shfl_xor(hi ? P2[5] : P2[7], 32, 64);
  union { unsigned u[4]; bf16x8 v; } f0, f1;
  f0.u[0] = hi ? e0 : P2[0]; f0.u[1] = hi ? e1 : P2[1];
  f0.u[2] = hi ? P2[2] : e0; f0.u[3] = hi ? P2[3] : e1;
  f1.u[0] = hi ? e2 : P2[4]; f1.u[1] = hi ? e3 : P2[5];
  f1.u[2] = hi ? P2[6] : e2; f1.u[3] = hi ? P2[7] : e3;
#pragma unroll
  for (int dt = 0; dt < 2; ++dt) {
    int row = dt * 32 + lq;
    bf16x8 v0 = *(const bf16x8*)(Vsb + row * 128 + ((4 * sub + hi) ^ (row & 7)) * 16);
    bf16x8 v1 = *(const bf16x8*)(Vsb + row * 128 + ((4 * sub + 2 + hi) ^ (row & 7)) * 16);
    f32x16& o = dt ? o1 : o0;
    o = __builtin_amdgcn_mfma_f32_32x32x16_bf16(v0, f0.v, o, 0, 0, 0);
    o = __builtin_amdgcn_mfma_f32_32x32x16_bf16(v1, f1.v, o, 0, 0, 0);
  }
}

__global__ __launch_bounds__(256) void k_attn(
    const short* __restrict__ qg, const short* __restrict__ kg,
    const short* __restrict__ vtg, const int* __restrict__ pme,
    short* __restrict__ yb)
{
  __shared__ short Ks[64 * 64];      // [key][d], swizzled chunk c at c^(key&7)
  __shared__ short Vs[64 * 64];      // [d][key], swizzled chunk c at c^(d&7)
  __shared__ int s_haspm;
  const int tid = threadIdx.x, lane = tid & 63, w = tid >> 6;
  const int hi = lane >> 5, lq = lane & 31;
  const int id = blockIdx.x;
  const int bh = id & 63, b = bh >> 3, h = bh & 7, tt = b & 3;
  const int q0 = (id >> 6) << 7;
  const char* Qb = (const char*)(qg + ((size_t)bh * TSEQ + q0) * HD);
  const char* Kb = (const char*)(kg + (size_t)bh * TSEQ * HD);
  const char* Vb = (const char*)(vtg + (size_t)bh * HD * TSEQ);

  if (tid == 0) s_haspm = 0;
  __syncthreads();
  if (tid < 128 && pme[tt * TSEQ + q0 + tid]) s_haspm = 1;
  __syncthreads();
  const int nkt = s_haspm ? (TSEQ / 64) : ((q0 >> 6) + 2);

  const int q_g = q0 + w * 32 + lq;
  const int pmrow = pme[tt * TSEQ + q_g];

  // Q fragments: qf[dk] = Q[q=lq][16*dk + 8*hi .. +7]
  bf16x8 qf[4];
#pragma unroll
  for (int dk = 0; dk < 4; ++dk)
    qf[dk] = *(const bf16x8*)(Qb + (size_t)(w * 32 + lq) * 128 + dk * 32 + hi * 16);

  float mrun = -__builtin_inff(), lrun = 0.0f;
  f32x16 o0 = {}, o1 = {};   // O^T: rows = d (crow pattern), col = q = lq

  const int stg_row = (w << 3) + (lane >> 3);          // 0..31 (+32 for is=1)
  const int stg_cl = (lane & 7) ^ ((lane >> 3) & 7);   // pre-swizzled source chunk

  for (int kt = 0; kt < nkt; ++kt) {
    __syncthreads();
#pragma unroll
    for (int is = 0; is < 2; ++is) {
      int row = is * 32 + stg_row;
      gload_lds16(Kb + (size_t)(kt * 64 + row) * 128 + stg_cl * 16,
                  (char*)Ks + is * 4096 + w * 1024);
      gload_lds16(Vb + (size_t)row * 2048 + kt * 128 + stg_cl * 16,
                  (char*)Vs + is * 4096 + w * 1024);
    }
    __syncthreads();

    // S^T = K · Q^T : s0 = keys [kb, kb+32), s1 = keys [kb+32, kb+64)
    f32x16 s0 = {}, s1 = {};
#pragma unroll
    for (int dk = 0; dk < 4; ++dk) {
      int row0 = lq, row1 = 32 + lq;
      bf16x8 kf0 = *(const bf16x8*)((const char*)Ks + row0 * 128 + ((2 * dk + hi) ^ (row0 & 7)) * 16);
      bf16x8 kf1 = *(const bf16x8*)((const char*)Ks + row1 * 128 + ((2 * dk + hi) ^ (row1 & 7)) * 16);
      s0 = __builtin_amdgcn_mfma_f32_32x32x16_bf16(kf0, qf[dk], s0, 0, 0, 0);
      s1 = __builtin_amdgcn_mfma_f32_32x32x16_bf16(kf1, qf[dk], s1, 0, 0, 0);
    }

    // scale + mask (wave-uniform fast paths)
    const int kb_ = kt * 64;
    if (kb_ + 63 <= q0 + w * 32) {
#pragma unroll
      for (int r = 0; r < 16; ++r) { s0[r] *= 0.125f; s1[r] *= 0.125f; }
    } else if (kb_ > q0 + w * 32 + 31) {
#pragma unroll
      for (int r = 0; r < 16; ++r) {
        s0[r] = pmrow ? s0[r] * 0.125f : -1e30f;
        s1[r] = pmrow ? s1[r] * 0.125f : -1e30f;
      }
    } else {
#pragma unroll
      for (int r = 0; r < 16; ++r) {
        int crow = (r & 3) + 8 * (r >> 2) + 4 * hi;
        s0[r] = ((kb_ + crow <= q_g) || pmrow) ? s0[r] * 0.125f : -1e30f;
        s1[r] = ((kb_ + 32 + crow <= q_g) || pmrow) ? s1[r] * 0.125f : -1e30f;
      }
    }

    // online softmax — lane-local (q = lq), one cross-lane hop
    float mx = s0[0];
#pragma unroll
    for (int r = 1; r < 16; ++r) mx = fmaxf(mx, s0[r]);
#pragma unroll
    for (int r = 0; r < 16; ++r) mx = fmaxf(mx, s1[r]);
    mx = fmaxf(mx, __shfl_xor(mx, 32, 64));
    float nm = fmaxf(mrun, mx);
    float sc = __expf(mrun - nm);
    mrun = nm;
    float rs = 0.0f;
#pragma unroll
    for (int r = 0; r < 16; ++r) { s0[r] = __expf(s0[r] - nm); rs += s0[r]; }
#pragma unroll
    for (int r = 0; r < 16; ++r) { s1[r] = __expf(s1[r] - nm); rs += s1[r]; }
    rs += __shfl_xor(rs, 32, 64);
    lrun = lrun * sc + rs;
#pragma unroll
    for (int r = 0; r < 16; ++r) { o0[r] *= sc; o1[r] *= sc; }

    // O^T += V^T · P  (P assembled in-register)
    pv_step(s0, 0, hi, lq, (const char*)Vs, o0, o1);
    pv_step(s1, 1, hi, lq, (const char*)Vs, o0, o1);
  }

  // epilogue: y[b][q][h*64 + d], d = dt*32 + crow(r,hi)
  const float inv = 1.0f / lrun;
  short* yrow = yb + ((size_t)b * TSEQ + q_g) * CEMB + h * HD;
#pragma unroll
  for (int dt = 0; dt < 2; ++dt) {
    const f32x16& o = dt ? o1 : o0;
#pragma unroll
    for (int g = 0; g < 4; ++g) {
      short4 pk;
      pk.x = f2b(o[4 * g + 0] * inv);
      pk.y = f2b(o[4 * g + 1] * inv);
      pk.z = f2b(o[4 * g + 2] * inv);
      pk.w = f2b(o[4 * g + 3] * inv);
      *(short4*)(yrow + dt * 32 + 8 * g + 4 * hi) = pk;
    }
  }
}

// ---------------------------------------------------------------------------
extern "C" void kernel_launch(void* const* d_in, const int* in_sizes, int n_in,
                              void* d_out, int out_size, void* d_ws, size_t ws_size,
                              hipStream_t stream) {
  const float* x     = (const float*)d_in[0];
  const void*  pmask = d_in[1];
  const float* Wqkv  = (const float*)d_in[2];
  const float* bqkv  = (const float*)d_in[3];
  const float* Wproj = (const float*)d_in[4];
  const float* bproj = (const float*)d_in[5];
  float* out = (float*)d_out;
  char* ws = (char*)d_ws;

  const size_t OFF_XB  = 0;
  const size_t OFF_WQT = 8388608;
  const size_t OFF_WPT = 9961472;
  const size_t OFF_Q   = 10485760;
  const size_t OFF_K   = 18874368;
  const size_t OFF_VT  = 27262976;
  const size_t OFF_Y   = 35651584;
  const size_t OFF_PM  = 44040192;
  const size_t NEED    = 44056576;
  if (ws_size < NEED) return;

  short* xb  = (short*)(ws + OFF_XB);
  short* wqT = (short*)(ws + OFF_WQT);
  short* wpT = (short*)(ws + OFF_WPT);
  short* qb  = (short*)(ws + OFF_Q);
  short* kb  = (short*)(ws + OFF_K);
  short* vtb = (short*)(ws + OFF_VT);
  short* yb  = (short*)(ws + OFF_Y);
  int*   pme = (int*)(ws + OFF_PM);

  k_mask<<<dim3(1), dim3(256), 0, stream>>>(pmask, pme);
  k_cvt_x<<<dim3(4096), dim3(256), 0, stream>>>(x, xb, (BB * TSEQ * CEMB) / 4);
  k_transpose_w<<<dim3((CEMB * 3 * CEMB + 255) / 256), dim3(256), 0, stream>>>(Wqkv, wqT, CEMB, 3 * CEMB);
  k_transpose_w<<<dim3((CEMB * CEMB + 255) / 256), dim3(256), 0, stream>>>(Wproj, wpT, CEMB, CEMB);
  k_gemm<0><<<dim3(12, 64), dim3(256), 0, stream>>>(xb, wqT, bqkv, qb, kb, vtb, nullptr);
  k_attn<<<dim3(512), dim3(256), 0, stream>>>(qb, kb, vtb, pme, yb);
  k_gemm<1><<<dim3(4, 64), dim3(256), 0, stream>>>(yb, wpT, bproj, nullptr, nullptr, nullptr, out);
}

// Round 3
// 99.469 us; speedup vs baseline: 1.3738x; 1.1423x over previous
//
#include <hip/hip_runtime.h>
#include <hip/hip_bf16.h>

// Problem constants
#define BB 8
#define TT_ 4
#define TSEQ 1024
#define CEMB 512
#define NH 8
#define HD 64

typedef __attribute__((ext_vector_type(8))) short bf16x8;
typedef __attribute__((ext_vector_type(4))) float f32x4;
typedef __attribute__((ext_vector_type(16))) float f32x16;

#define AS1 __attribute__((address_space(1)))
#define AS3 __attribute__((address_space(3)))

__device__ __forceinline__ void gload_lds16(const void* g, void* l) {
  __builtin_amdgcn_global_load_lds((const AS1 unsigned int*)g, (AS3 unsigned int*)l, 16, 0, 0);
}

__device__ __forceinline__ short f2b(float f) {
  union { float f; unsigned u; } v; v.f = f;
  unsigned r = v.u + 0x7FFFu + ((v.u >> 16) & 1u);
  return (short)(r >> 16);
}

__device__ __forceinline__ unsigned pack2(float a, float b) {
  return (unsigned)(unsigned short)f2b(a) | ((unsigned)(unsigned short)f2b(b) << 16);
}

// ---------------------------------------------------------------------------
// Mask dtype detection + expansion (unchanged).
// ---------------------------------------------------------------------------
__global__ __launch_bounds__(256) void k_mask(const void* __restrict__ pin, int* __restrict__ pme) {
  __shared__ int bad_f32, any_f32, bad_i32, any_i32, bad_u16, any_u16;
  if (threadIdx.x == 0) { bad_f32 = any_f32 = bad_i32 = any_i32 = bad_u16 = any_u16 = 0; }
  __syncthreads();
  const unsigned char* pb = (const unsigned char*)pin;
  const float* pf = (const float*)pin;
  const int* pi = (const int*)pin;
  const unsigned short* ph = (const unsigned short*)pin;
  for (int i = threadIdx.x; i < 1024; i += 256) {
    float fv = pf[i];
    if (fv != 0.0f && fv != 1.0f) bad_f32 = 1;
    if (fv == 1.0f) any_f32 = 1;
    int iv = pi[i];
    if (iv != 0 && iv != 1) bad_i32 = 1;
    if (iv == 1) any_i32 = 1;
  }
  for (int i = threadIdx.x; i < 2048; i += 256) {
    unsigned short hv = ph[i];
    if (hv != 0 && hv != 0x3F80u && hv != 0x3C00u) bad_u16 = 1;
    if (hv == 0x3F80u || hv == 0x3C00u) any_u16 = 1;
  }
  __syncthreads();
  int mode = 3;
  if (!bad_f32 && any_f32) mode = 0;
  else if (!bad_i32 && any_i32) mode = 1;
  else if (!bad_u16 && any_u16) mode = 2;
  for (int i = threadIdx.x; i < TT_ * TSEQ; i += 256) {
    int v;
    if (mode == 0)      v = (pf[i] != 0.0f);
    else if (mode == 1) v = (pi[i] != 0);
    else if (mode == 2) v = (ph[i] != 0);
    else                v = (pb[i] != 0);
    pme[i] = v;
  }
}

__global__ __launch_bounds__(256) void k_cvt_x(const float* __restrict__ x, short* __restrict__ xb, int n4) {
  int i = blockIdx.x * 256 + threadIdx.x;
  if (i < n4) {
    float4 v = ((const float4*)x)[i];
    short4 o;
    o.x = f2b(v.x); o.y = f2b(v.y); o.z = f2b(v.z); o.w = f2b(v.w);
    ((short4*)xb)[i] = o;
  }
}

// W [K][N] f32 -> Wt [N][K] bf16, 64x64 LDS tile, coalesced both sides.
__global__ __launch_bounds__(256) void k_transpose_w(const float* __restrict__ w, short* __restrict__ wt,
                                                     int K, int N) {
  __shared__ float t[64][65];
  const int tx = threadIdx.x & 15, ty = threadIdx.x >> 4;   // 16x16 threads
  const int n0 = blockIdx.x * 64, k0 = blockIdx.y * 64;
#pragma unroll
  for (int i = 0; i < 4; ++i) {
    int kr = i * 16 + ty;
    float4 v = *(const float4*)&w[(size_t)(k0 + kr) * N + n0 + tx * 4];
    t[tx * 4 + 0][kr] = v.x; t[tx * 4 + 1][kr] = v.y;
    t[tx * 4 + 2][kr] = v.z; t[tx * 4 + 3][kr] = v.w;
  }
  __syncthreads();
#pragma unroll
  for (int i = 0; i < 4; ++i) {
    int nr = i * 16 + ty;
    short4 o;
    o.x = f2b(t[nr][tx * 4 + 0]); o.y = f2b(t[nr][tx * 4 + 1]);
    o.z = f2b(t[nr][tx * 4 + 2]); o.w = f2b(t[nr][tx * 4 + 3]);
    *(short4*)&wt[(size_t)(n0 + nr) * K + k0 + tx * 4] = o;
  }
}

// ---------------------------------------------------------------------------
// GEMM: 128x128 tile, 4 waves, BK=32, double-buffered 2-phase pipeline.
// ---------------------------------------------------------------------------
template<int MODE>
__global__ __launch_bounds__(256) void k_gemm(
    const short* __restrict__ A, const short* __restrict__ Bt,
    const float* __restrict__ bias,
    short* __restrict__ qb, short* __restrict__ kb, short* __restrict__ vtb,
    float* __restrict__ fout)
{
  __shared__ short As[2][128 * 32];
  __shared__ short Bs[2][128 * 32];
  const int tid = threadIdx.x, lane = tid & 63, w = tid >> 6;
  const int wm = w >> 1, wn = w & 1;
  const int n0 = blockIdx.x * 128, m0 = blockIdx.y * 128;
  f32x4 acc[4][4] = {};
  const char* Abase = (const char*)A + (size_t)m0 * 1024;
  const char* Bbase = (const char*)Bt + (size_t)n0 * 1024;
  const int rowL = w * 16 + (lane >> 2);
  const int colB = (lane & 3) * 16;

  auto stage = [&](int buf, int k0) {
#pragma unroll
    for (int is = 0; is < 2; ++is) {
      int row = is * 64 + rowL;
      gload_lds16(Abase + (size_t)row * 1024 + (size_t)(k0 * 2 + colB),
                  (char*)As[buf] + is * 4096 + w * 1024);
      gload_lds16(Bbase + (size_t)row * 1024 + (size_t)(k0 * 2 + colB),
                  (char*)Bs[buf] + is * 4096 + w * 1024);
    }
  };

  stage(0, 0);
  __syncthreads();               // drains vmcnt(0): buf0 ready
  int buf = 0;
  for (int k0 = 0; k0 < 512; k0 += 32) {
    if (k0 + 32 < 512) stage(buf ^ 1, k0 + 32);
    bf16x8 a[4], bfr[4];
#pragma unroll
    for (int mf = 0; mf < 4; ++mf)
      a[mf] = *(const bf16x8*)&As[buf][(wm * 64 + mf * 16 + (lane & 15)) * 32 + (lane >> 4) * 8];
#pragma unroll
    for (int nf = 0; nf < 4; ++nf)
      bfr[nf] = *(const bf16x8*)&Bs[buf][(wn * 64 + nf * 16 + (lane & 15)) * 32 + (lane >> 4) * 8];
#pragma unroll
    for (int mf = 0; mf < 4; ++mf)
#pragma unroll
      for (int nf = 0; nf < 4; ++nf)
        acc[mf][nf] = __builtin_amdgcn_mfma_f32_16x16x32_bf16(a[mf], bfr[nf], acc[mf][nf], 0, 0, 0);
    __syncthreads();             // reads of buf done + stage(buf^1) drained
    buf ^= 1;
  }

#pragma unroll
  for (int nf = 0; nf < 4; ++nf) {
    const int n_g = n0 + wn * 64 + nf * 16 + (lane & 15);
    const float bv = bias[n_g];
    if (MODE == 0) {
      const int which = n_g >> 9;
      const int c = n_g & 511;
      const int h = c >> 6, d = c & 63;
#pragma unroll
      for (int mf = 0; mf < 4; ++mf) {
        const int mb = m0 + wm * 64 + mf * 16 + ((lane >> 4) << 2);
        const int b = mb >> 10, t0 = mb & 1023;
        const int b8h = b * NH + h;
        if (which == 2) {
          short4 pk;
          pk.x = f2b(acc[mf][nf][0] + bv);
          pk.y = f2b(acc[mf][nf][1] + bv);
          pk.z = f2b(acc[mf][nf][2] + bv);
          pk.w = f2b(acc[mf][nf][3] + bv);
          *(short4*)&vtb[((size_t)b8h * HD + d) * TSEQ + t0] = pk;
        } else {
          short* dst = (which == 0) ? qb : kb;
          size_t base = ((size_t)b8h * TSEQ + t0) * HD + d;
#pragma unroll
          for (int r = 0; r < 4; ++r)
            dst[base + (size_t)r * HD] = f2b(acc[mf][nf][r] + bv);
        }
      }
    } else {
#pragma unroll
      for (int mf = 0; mf < 4; ++mf) {
        const int mb = m0 + wm * 64 + mf * 16 + ((lane >> 4) << 2);
#pragma unroll
        for (int r = 0; r < 4; ++r)
          fout[(size_t)(mb + r) * 512 + n_g] = acc[mf][nf][r] + bv;
      }
    }
  }
}

// ---------------------------------------------------------------------------
// Flash attention v3 — swapped-operand 32x32 + double-buffered K/V pipeline,
// exp2-domain softmax with defer-max, setprio around MFMA clusters.
// ---------------------------------------------------------------------------
__device__ __forceinline__ void pv_step(
    f32x16 p, int sub, int hi, int lq, const char* Vsb, f32x16& o0, f32x16& o1)
{
  unsigned P2[8];
#pragma unroll
  for (int i = 0; i < 8; ++i) P2[i] = pack2(p[2 * i], p[2 * i + 1]);
  unsigned e0 = __shfl_xor(hi ? P2[0] : P2[2], 32, 64);
  unsigned e1 = __shfl_xor(hi ? P2[1] : P2[3], 32, 64);
  unsigned e2 = __shfl_xor(hi ? P2[4] : P2[6], 32, 64);
  unsigned e3 = __shfl_xor(hi ? P2[5] : P2[7], 32, 64);
  union { unsigned u[4]; bf16x8 v; } f0, f1;
  f0.u[0] = hi ? e0 : P2[0]; f0.u[1] = hi ? e1 : P2[1];
  f0.u[2] = hi ? P2[2] : e0; f0.u[3] = hi ? P2[3] : e1;
  f1.u[0] = hi ? e2 : P2[4]; f1.u[1] = hi ? e3 : P2[5];
  f1.u[2] = hi ? P2[6] : e2; f1.u[3] = hi ? P2[7] : e3;
  __builtin_amdgcn_s_setprio(1);
#pragma unroll
  for (int dt = 0; dt < 2; ++dt) {
    int row = dt * 32 + lq;
    bf16x8 v0 = *(const bf16x8*)(Vsb + row * 128 + ((4 * sub + hi) ^ (row & 7)) * 16);
    bf16x8 v1 = *(const bf16x8*)(Vsb + row * 128 + ((4 * sub + 2 + hi) ^ (row & 7)) * 16);
    f32x16& o = dt ? o1 : o0;
    o = __builtin_amdgcn_mfma_f32_32x32x16_bf16(v0, f0.v, o, 0, 0, 0);
    o = __builtin_amdgcn_mfma_f32_32x32x16_bf16(v1, f1.v, o, 0, 0, 0);
  }
  __builtin_amdgcn_s_setprio(0);
}

__global__ __launch_bounds__(256) void k_attn(
    const short* __restrict__ qg, const short* __restrict__ kg,
    const short* __restrict__ vtg, const int* __restrict__ pme,
    short* __restrict__ yb)
{
  __shared__ short Ks[2 * 64 * 64];   // [buf][key][d], chunk c at c^(key&7)
  __shared__ short Vs[2 * 64 * 64];   // [buf][d][key], chunk c at c^(d&7)
  __shared__ int s_haspm;
  const int tid = threadIdx.x, lane = tid & 63, w = tid >> 6;
  const int hi = lane >> 5, lq = lane & 31;
  const int id = blockIdx.x;
  const int bh = id & 63, b = bh >> 3, h = bh & 7, tt = b & 3;
  const int q0 = (id >> 6) << 7;
  const char* Qb = (const char*)(qg + ((size_t)bh * TSEQ + q0) * HD);
  const char* Kb = (const char*)(kg + (size_t)bh * TSEQ * HD);
  const char* Vb = (const char*)(vtg + (size_t)bh * HD * TSEQ);

  const int stg_row = (w << 3) + (lane >> 3);
  const int stg_cl = (lane & 7) ^ ((lane >> 3) & 7);

  auto stage = [&](int buf, int kt) {
#pragma unroll
    for (int is = 0; is < 2; ++is) {
      int row = is * 32 + stg_row;
      gload_lds16(Kb + (size_t)(kt * 64 + row) * 128 + stg_cl * 16,
                  (char*)Ks + buf * 8192 + is * 4096 + w * 1024);
      gload_lds16(Vb + (size_t)row * 2048 + kt * 128 + stg_cl * 16,
                  (char*)Vs + buf * 8192 + is * 4096 + w * 1024);
    }
  };

  if (tid == 0) s_haspm = 0;
  stage(0, 0);
  const int q_g = q0 + w * 32 + lq;
  const int pmrow = pme[tt * TSEQ + q_g];
  // Q fragments
  bf16x8 qf[4];
#pragma unroll
  for (int dk = 0; dk < 4; ++dk)
    qf[dk] = *(const bf16x8*)(Qb + (size_t)(w * 32 + lq) * 128 + dk * 32 + hi * 16);
  __syncthreads();                       // flag init visible; stage(0) drained
  if (tid < 128 && pme[tt * TSEQ + q0 + tid]) s_haspm = 1;
  __syncthreads();
  const int nkt = s_haspm ? (TSEQ / 64) : ((q0 >> 6) + 2);

  const float SC = 0.18033688011112043f;   // 0.125 * log2(e)
  float mrun = -__builtin_inff(), lrun = 0.0f;
  f32x16 o0 = {}, o1 = {};

  int buf = 0;
  for (int kt = 0; kt < nkt; ++kt) {
    if (kt + 1 < nkt) stage(buf ^ 1, kt + 1);
    const char* Ksb = (const char*)Ks + buf * 8192;
    const char* Vsb = (const char*)Vs + buf * 8192;

    // S^T = K · Q^T
    f32x16 s0 = {}, s1 = {};
    __builtin_amdgcn_s_setprio(1);
#pragma unroll
    for (int dk = 0; dk < 4; ++dk) {
      int row0 = lq, row1 = 32 + lq;
      bf16x8 kf0 = *(const bf16x8*)(Ksb + row0 * 128 + ((2 * dk + hi) ^ (row0 & 7)) * 16);
      bf16x8 kf1 = *(const bf16x8*)(Ksb + row1 * 128 + ((2 * dk + hi) ^ (row1 & 7)) * 16);
      s0 = __builtin_amdgcn_mfma_f32_32x32x16_bf16(kf0, qf[dk], s0, 0, 0, 0);
      s1 = __builtin_amdgcn_mfma_f32_32x32x16_bf16(kf1, qf[dk], s1, 0, 0, 0);
    }
    __builtin_amdgcn_s_setprio(0);

    // scale (log2 domain) + mask
    const int kb_ = kt * 64;
    if (kb_ + 63 <= q0 + w * 32) {
#pragma unroll
      for (int r = 0; r < 16; ++r) { s0[r] *= SC; s1[r] *= SC; }
    } else if (kb_ > q0 + w * 32 + 31) {
#pragma unroll
      for (int r = 0; r < 16; ++r) {
        s0[r] = pmrow ? s0[r] * SC : -1e30f;
        s1[r] = pmrow ? s1[r] * SC : -1e30f;
      }
    } else {
#pragma unroll
      for (int r = 0; r < 16; ++r) {
        int crow = (r & 3) + 8 * (r >> 2) + 4 * hi;
        s0[r] = ((kb_ + crow <= q_g) || pmrow) ? s0[r] * SC : -1e30f;
        s1[r] = ((kb_ + 32 + crow <= q_g) || pmrow) ? s1[r] * SC : -1e30f;
      }
    }

    // online softmax, lane-local + one hop; defer-max (THR=8 in log2 units)
    float mx = s0[0];
#pragma unroll
    for (int r = 1; r < 16; ++r) mx = fmaxf(mx, s0[r]);
#pragma unroll
    for (int r = 0; r < 16; ++r) mx = fmaxf(mx, s1[r]);
    mx = fmaxf(mx, __shfl_xor(mx, 32, 64));
    if (!__all(mx <= mrun + 8.0f)) {
      float nm = fmaxf(mrun, mx);
      float sc = __builtin_amdgcn_exp2f(mrun - nm);
      lrun *= sc;
#pragma unroll
      for (int r = 0; r < 16; ++r) { o0[r] *= sc; o1[r] *= sc; }
      mrun = nm;
    }
    float rs = 0.0f;
#pragma unroll
    for (int r = 0; r < 16; ++r) { s0[r] = __builtin_amdgcn_exp2f(s0[r] - mrun); rs += s0[r]; }
#pragma unroll
    for (int r = 0; r < 16; ++r) { s1[r] = __builtin_amdgcn_exp2f(s1[r] - mrun); rs += s1[r]; }
    rs += __shfl_xor(rs, 32, 64);
    lrun += rs;

    // O^T += V^T · P
    pv_step(s0, 0, hi, lq, Vsb, o0, o1);
    pv_step(s1, 1, hi, lq, Vsb, o0, o1);

    __syncthreads();          // reads of buf done + stage(buf^1) drained
    buf ^= 1;
  }

  // epilogue
  const float inv = 1.0f / lrun;
  short* yrow = yb + ((size_t)b * TSEQ + q_g) * CEMB + h * HD;
#pragma unroll
  for (int dt = 0; dt < 2; ++dt) {
    const f32x16& o = dt ? o1 : o0;
#pragma unroll
    for (int g = 0; g < 4; ++g) {
      short4 pk;
      pk.x = f2b(o[4 * g + 0] * inv);
      pk.y = f2b(o[4 * g + 1] * inv);
      pk.z = f2b(o[4 * g + 2] * inv);
      pk.w = f2b(o[4 * g + 3] * inv);
      *(short4*)(yrow + dt * 32 + 8 * g + 4 * hi) = pk;
    }
  }
}

// ---------------------------------------------------------------------------
extern "C" void kernel_launch(void* const* d_in, const int* in_sizes, int n_in,
                              void* d_out, int out_size, void* d_ws, size_t ws_size,
                              hipStream_t stream) {
  const float* x     = (const float*)d_in[0];
  const void*  pmask = d_in[1];
  const float* Wqkv  = (const float*)d_in[2];
  const float* bqkv  = (const float*)d_in[3];
  const float* Wproj = (const float*)d_in[4];
  const float* bproj = (const float*)d_in[5];
  float* out = (float*)d_out;
  char* ws = (char*)d_ws;

  const size_t OFF_XB  = 0;
  const size_t OFF_WQT = 8388608;
  const size_t OFF_WPT = 9961472;
  const size_t OFF_Q   = 10485760;
  const size_t OFF_K   = 18874368;
  const size_t OFF_VT  = 27262976;
  const size_t OFF_Y   = 35651584;
  const size_t OFF_PM  = 44040192;
  const size_t NEED    = 44056576;
  if (ws_size < NEED) return;

  short* xb  = (short*)(ws + OFF_XB);
  short* wqT = (short*)(ws + OFF_WQT);
  short* wpT = (short*)(ws + OFF_WPT);
  short* qb  = (short*)(ws + OFF_Q);
  short* kb  = (short*)(ws + OFF_K);
  short* vtb = (short*)(ws + OFF_VT);
  short* yb  = (short*)(ws + OFF_Y);
  int*   pme = (int*)(ws + OFF_PM);

  k_mask<<<dim3(1), dim3(256), 0, stream>>>(pmask, pme);
  k_cvt_x<<<dim3(4096), dim3(256), 0, stream>>>(x, xb, (BB * TSEQ * CEMB) / 4);
  k_transpose_w<<<dim3(24, 8), dim3(256), 0, stream>>>(Wqkv, wqT, CEMB, 3 * CEMB);
  k_transpose_w<<<dim3(8, 8), dim3(256), 0, stream>>>(Wproj, wpT, CEMB, CEMB);
  k_gemm<0><<<dim3(12, 64), dim3(256), 0, stream>>>(xb, wqT, bqkv, qb, kb, vtb, nullptr);
  k_attn<<<dim3(512), dim3(256), 0, stream>>>(qb, kb, vtb, pme, yb);
  k_gemm<1><<<dim3(4, 64), dim3(256), 0, stream>>>(yb, wpT, bproj, nullptr, nullptr, nullptr, out);
}